// Round 2
// baseline (3094.836 us; speedup 1.0000x reference)
//
#include <hip/hip_runtime.h>
#include <hip/hip_bf16.h>

typedef unsigned short u16;
typedef unsigned int u32;

#define Tn 128
#define Fn 512
#define HWc (Tn*Fn)     // 65536 elems per channel (conv tensors)
#define EPS 1e-5f

__device__ __forceinline__ float b2f(u16 x){ return __uint_as_float(((u32)x)<<16); }
__device__ __forceinline__ u16 f2b(float f){
  __hip_bfloat16 h = __float2bfloat16(f);
  return *reinterpret_cast<u16*>(&h);
}

// ---------------- zero stats ----------------
__global__ void zero_stats(float* raw){
  int i = threadIdx.x;
  if (i < 160) raw[i] = 0.f;   // 5 stages * 32 floats (sum[16], sumsq[16])
}

// ---------------- convert+copy x (fp32) into B72 channels 48..72 (bf16) ----------------
__global__ __launch_bounds__(256) void copy_x(const float* __restrict__ x, u16* __restrict__ b72){
  int idx = blockIdx.x*256 + threadIdx.x;       // 786432 threads, 8 elems each
  long e = (long)idx*8;
  int ch = (int)(e / HWc);                      // 0..95 = b*24+c
  long r = e - (long)ch*HWc;
  int b = ch/24, c = ch%24;
  float4 v0 = *(const float4*)(x + e);
  float4 v1 = *(const float4*)(x + e + 4);
  union { int4 v; u16 u[8]; } ov;
  ov.u[0]=f2b(v0.x); ov.u[1]=f2b(v0.y); ov.u[2]=f2b(v0.z); ov.u[3]=f2b(v0.w);
  ov.u[4]=f2b(v1.x); ov.u[5]=f2b(v1.y); ov.u[6]=f2b(v1.z); ov.u[7]=f2b(v1.w);
  *(int4*)(b72 + ((long)(b*72 + 48 + c))*HWc + r) = ov.v;
}

// ---------------- direct 3x3 conv, bf16 in, fp32 weights, fp32 acc, bf16 out ----------------
template<int CIN>
__global__ __launch_bounds__(256)
void conv3x3(const u16* __restrict__ in, int in_cstride, int in_coff,
             const float* __restrict__ wt, const float* __restrict__ bias,
             u16* __restrict__ out){
  __shared__ float sw[24*CIN*9];
  for (int i = threadIdx.x; i < 24*CIN*9; i += 256) sw[i] = wt[i];
  __syncthreads();

  int gid = blockIdx.x*256 + threadIdx.x;   // 786432 total
  int fs = (gid & 63)*8;
  int t  = (gid >> 6) & 127;
  int oc = gid >> 13;            // 0..95
  int o  = oc % 24;
  int b  = oc / 24;

  float acc[8];
  float bv = bias[o];
  #pragma unroll
  for (int j=0;j<8;j++) acc[j]=bv;

  const float* wo = &sw[o*CIN*9];
  for (int i=0;i<CIN;i++){
    const u16* base = in + ((long)(b*in_cstride + in_coff + i))*HWc;
    float v[3][10];
    #pragma unroll
    for (int dt=0; dt<3; dt++){
      int rrow = t + dt - 1;
      bool rok = (rrow >= 0) && (rrow < Tn);
      const u16* rp = base + (long)(rok ? rrow : 0)*Fn;
      #pragma unroll
      for (int k=0;k<10;k++){
        int f = fs - 1 + k;
        bool ok = rok && (f >= 0) && (f < Fn);
        v[dt][k] = ok ? b2f(rp[f]) : 0.f;
      }
    }
    const float* wi = wo + i*9;
    #pragma unroll
    for (int dt=0; dt<3; dt++){
      #pragma unroll
      for (int df=0; df<3; df++){
        float wv = wi[dt*3+df];
        #pragma unroll
        for (int j=0;j<8;j++) acc[j] += v[dt][df+j]*wv;
      }
    }
  }
  union { int4 v; u16 u[8]; } ov;
  #pragma unroll
  for (int j=0;j<8;j++) ov.u[j] = f2b(acc[j]);
  long obase = (((long)(b*24 + o))*Tn + t)*Fn + fs;
  *(int4*)(out + obase) = ov.v;
}

// ---------------- group stats (sum, sumsq) over contiguous bf16 ranges ----------------
__global__ __launch_bounds__(256)
void stats_kernel(const u16* __restrict__ src, float* __restrict__ raw,
                  long per_group, int nblk){
  int g   = blockIdx.x / nblk;
  int sub = blockIdx.x - g*nblk;
  long chunk = per_group / nblk;           // multiple of 2048
  const u16* base = src + (long)g*per_group + (long)sub*chunk;
  float s=0.f, ss=0.f;
  for (long e = (long)threadIdx.x*8; e < chunk; e += 2048){
    union { int4 v; u16 u[8]; } pk;
    pk.v = *(const int4*)(base + e);
    #pragma unroll
    for (int j=0;j<8;j++){ float f=b2f(pk.u[j]); s+=f; ss+=f*f; }
  }
  #pragma unroll
  for (int off=32; off>0; off>>=1){ s += __shfl_down(s,off,64); ss += __shfl_down(ss,off,64); }
  __shared__ float rs[4], rss[4];
  int wid = threadIdx.x >> 6;
  if ((threadIdx.x & 63)==0){ rs[wid]=s; rss[wid]=ss; }
  __syncthreads();
  if (threadIdx.x==0){
    s  = rs[0]+rs[1]+rs[2]+rs[3];
    ss = rss[0]+rss[1]+rss[2]+rss[3];
    atomicAdd(&raw[g], s);
    atomicAdd(&raw[16+g], ss);
  }
}

__global__ void finalize_stats(const float* __restrict__ raw, float* __restrict__ fin, float invN){
  int g = threadIdx.x;
  if (g < 16){
    float m = raw[g]*invN;
    float v = raw[16+g]*invN - m*m;
    fin[g] = m;
    fin[16+g] = rsqrtf(v + EPS);
  }
}

// ---------------- normalize + relu (bf16 src/dst, fp32 params, layout remap) ----------------
__global__ __launch_bounds__(256)
void norm_relu(const u16* __restrict__ src, u16* __restrict__ dst,
               const float* __restrict__ gw, const float* __restrict__ gb,
               const float* __restrict__ fin, long hw, int dstC, int dcoff){
  long idx = ((long)blockIdx.x*256 + threadIdx.x)*8;
  int ch = (int)(idx / hw);            // 0..95 = b*24+c
  long r = idx - (long)ch*hw;
  int b = ch/24, c = ch%24;
  int g = b*4 + c/6;
  float m = fin[g], is = fin[16+g];
  float sc = is * gw[c];
  float off = gb[c] - m*sc;
  union { int4 v; u16 u[8]; } pk;
  pk.v = *(const int4*)(src + idx);
  union { int4 v; u16 u[8]; } ov;
  #pragma unroll
  for (int j=0;j<8;j++){
    float f = b2f(pk.u[j])*sc + off;
    ov.u[j] = f2b(f > 0.f ? f : 0.f);
  }
  *(int4*)(dst + ((long)(b*dstC + dcoff + c))*hw + r) = ov.v;
}

// ---------------- fp32 tiled GEMM: C[M,N](bf16) = A[M,K](bf16) * W[N,K](fp32)^T ----------------
__global__ __launch_bounds__(256)
void gemm_bt(const u16* __restrict__ A, const float* __restrict__ W, u16* __restrict__ C,
             int M, int N, int K){
  __shared__ float As[64][17];
  __shared__ float Ws[64][17];
  int m0 = blockIdx.y*64;
  int n0 = blockIdx.x*64;
  int tid = threadIdx.x;
  int tx = tid & 15, ty = tid >> 4;
  float acc[4][4] = {};
  int row = tid >> 2, kq = (tid & 3)*4;
  for (int kt=0; kt<K; kt+=16){
    ushort4 av = *(const ushort4*)(A + (long)(m0+row)*K + kt + kq);
    As[row][kq+0]=b2f(av.x); As[row][kq+1]=b2f(av.y); As[row][kq+2]=b2f(av.z); As[row][kq+3]=b2f(av.w);
    float4 wv = *(const float4*)(W + (long)(n0+row)*K + kt + kq);
    Ws[row][kq+0]=wv.x; Ws[row][kq+1]=wv.y; Ws[row][kq+2]=wv.z; Ws[row][kq+3]=wv.w;
    __syncthreads();
    #pragma unroll
    for (int kk=0; kk<16; kk++){
      float a_[4], b_[4];
      #pragma unroll
      for (int r=0;r<4;r++){ a_[r]=As[ty*4+r][kk]; b_[r]=Ws[tx*4+r][kk]; }
      #pragma unroll
      for (int r=0;r<4;r++)
        #pragma unroll
        for (int s2=0;s2<4;s2++) acc[r][s2] += a_[r]*b_[s2];
    }
    __syncthreads();
  }
  #pragma unroll
  for (int r=0;r<4;r++)
    #pragma unroll
    for (int s2=0;s2<4;s2++)
      C[(long)(m0+ty*4+r)*N + n0+tx*4+s2] = f2b(acc[r][s2]);
}

// ---------------- attention: att[4][6] (all fp32 inputs) ----------------
__global__ void attention_kernel(const float* __restrict__ c, const float* __restrict__ wq,
                                 const float* __restrict__ bq, const float* __restrict__ keys,
                                 float* __restrict__ att){
  __shared__ float q[4][32];
  __shared__ float s[4][6];
  int t = threadIdx.x;
  if (t < 128){
    int b = t >> 5, k = t & 31;
    float a = bq[k];
    for (int j=0;j<32;j++) a += c[b*32+j] * wq[k*32+j];
    q[b][k] = a;
  }
  __syncthreads();
  if (t < 24){
    int b = t/6, n = t%6;
    float a = 0.f;
    for (int k=0;k<32;k++) a += q[b][k]*keys[k*6+n];
    s[b][n] = a * 0.17677669529663689f;   // 1/sqrt(32)
  }
  __syncthreads();
  if (t < 4){
    float mx = -1e30f;
    for (int n=0;n<6;n++) mx = fmaxf(mx, s[t][n]);
    float e[6], sm=0.f;
    for (int n=0;n<6;n++){ e[n]=expf(s[t][n]-mx); sm+=e[n]; }
    for (int n=0;n<6;n++) att[t*6+n] = e[n]/sm;
  }
}

// ---------------- final: out(fp32) = x_ + sum_n relu(gn2(h2))[...,n]*att[b,n] ----------------
__global__ __launch_bounds__(256)
void final_mix(const u16* __restrict__ h2, const u16* __restrict__ xr,
               const float* __restrict__ gw, const float* __restrict__ gb,
               const float* __restrict__ fin, const float* __restrict__ att,
               float* __restrict__ out){
  int gid = blockIdx.x*256 + threadIdx.x;   // 1,572,864 total (4 f per thread)
  int fq = gid & 127;
  int t  = (gid >> 7) & 127;
  int bc = gid >> 14;          // 0..95
  int c  = bc % 24, b = bc / 24;
  int g  = b*4 + c/6;
  float m = fin[g], is = fin[16+g];
  float sc = is * gw[c];
  float off = gb[c] - m*sc;
  float a[6];
  #pragma unroll
  for (int n=0;n<6;n++) a[n] = att[b*6+n];

  long hbase = (((long)bc*Tn + t))*3072 + (long)fq*24;
  union { int4 v[3]; u16 u[24]; } hv;
  const int4* hp = (const int4*)(h2 + hbase);
  hv.v[0]=hp[0]; hv.v[1]=hp[1]; hv.v[2]=hp[2];

  long xbase = (((long)bc*Tn + t))*Fn + (long)fq*4;
  union { unsigned long long q; u16 u[4]; } xv;
  xv.q = *(const unsigned long long*)(xr + xbase);

  float4 ov;
  float* op = &ov.x;
  #pragma unroll
  for (int j=0;j<4;j++){
    float accv = b2f(xv.u[j]);
    #pragma unroll
    for (int n=0;n<6;n++){
      float hvf = b2f(hv.u[j*6+n])*sc + off;
      hvf = hvf > 0.f ? hvf : 0.f;
      accv += hvf * a[n];
    }
    op[j] = accv;
  }
  *(float4*)(out + xbase) = ov;
}

extern "C" void kernel_launch(void* const* d_in, const int* in_sizes, int n_in,
                              void* d_out, int out_size, void* d_ws, size_t ws_size,
                              hipStream_t stream){
  const float* x   = (const float*)d_in[0];
  const float* c   = (const float*)d_in[1];
  const float* cw0 = (const float*)d_in[2];  const float* cb0 = (const float*)d_in[3];
  const float* gw0 = (const float*)d_in[4];  const float* gb0 = (const float*)d_in[5];
  const float* cw1 = (const float*)d_in[6];  const float* cb1 = (const float*)d_in[7];
  const float* gw1 = (const float*)d_in[8];  const float* gb1 = (const float*)d_in[9];
  const float* cw2 = (const float*)d_in[10]; const float* cb2 = (const float*)d_in[11];
  const float* gw2 = (const float*)d_in[12]; const float* gb2 = (const float*)d_in[13];
  const float* tw1 = (const float*)d_in[14]; const float* tg1w= (const float*)d_in[15]; const float* tg1b=(const float*)d_in[16];
  const float* tw2 = (const float*)d_in[17]; const float* tg2w= (const float*)d_in[18]; const float* tg2b=(const float*)d_in[19];
  const float* wqp = (const float*)d_in[20]; const float* bqp = (const float*)d_in[21]; const float* keys=(const float*)d_in[22];

  char* ws = (char*)d_ws;
  u16* xr = (u16*)(ws + 0);                        // 12,582,912 B  [4,24,128,512] bf16
  u16* h1 = (u16*)(ws + 12582912);                 //  4,718,592 B  [12288,192] bf16
  float* statsRaw = (float*)(ws + 17301504);       // 5*32 floats
  float* statsFin = (float*)(ws + 17301504 + 1024);
  float* att      = (float*)(ws + 17301504 + 2048);
  char* A3 = ws + 17305600;
  u16* b72 = (u16*)A3;                             // 37,748,736 B  [4,72,128,512] bf16
  u16* Y   = (u16*)(A3 + 37748736);                // 12,582,912 B  conv scratch
  u16* h2  = (u16*)A3;                             // 75,497,472 B  [12288,3072] bf16 (reuses conv region)

  zero_stats<<<1,256,0,stream>>>(statsRaw);
  copy_x<<<3072,256,0,stream>>>(x, b72);

  // ---- conv block 0 ----
  conv3x3<24><<<3072,256,0,stream>>>(b72, 72, 48, cw0, cb0, Y);
  stats_kernel<<<256,256,0,stream>>>(Y, statsRaw+0, 393216L, 16);
  finalize_stats<<<1,16,0,stream>>>(statsRaw+0, statsFin+0, 1.f/393216.f);
  norm_relu<<<3072,256,0,stream>>>(Y, b72, gw0, gb0, statsFin+0, (long)HWc, 72, 24);

  // ---- conv block 1 ----
  conv3x3<48><<<3072,256,0,stream>>>(b72, 72, 24, cw1, cb1, Y);
  stats_kernel<<<256,256,0,stream>>>(Y, statsRaw+32, 393216L, 16);
  finalize_stats<<<1,16,0,stream>>>(statsRaw+32, statsFin+32, 1.f/393216.f);
  norm_relu<<<3072,256,0,stream>>>(Y, b72, gw1, gb1, statsFin+32, (long)HWc, 72, 0);

  // ---- conv block 2 -> x_ ----
  conv3x3<72><<<3072,256,0,stream>>>(b72, 72, 0, cw2, cb2, Y);
  stats_kernel<<<256,256,0,stream>>>(Y, statsRaw+64, 393216L, 16);
  finalize_stats<<<1,16,0,stream>>>(statsRaw+64, statsFin+64, 1.f/393216.f);
  norm_relu<<<3072,256,0,stream>>>(Y, xr, gw2, gb2, statsFin+64, (long)HWc, 24, 0);

  // ---- TDF: gemm1 (12288x192x512) + GN + relu ----
  gemm_bt<<<dim3(3,192),256,0,stream>>>(xr, tw1, h1, 12288, 192, 512);
  stats_kernel<<<128,256,0,stream>>>(h1, statsRaw+96, 147456L, 8);
  finalize_stats<<<1,16,0,stream>>>(statsRaw+96, statsFin+96, 1.f/147456.f);
  norm_relu<<<1152,256,0,stream>>>(h1, h1, tg1w, tg1b, statsFin+96, 24576L, 24, 0);

  // ---- TDF: gemm2 (12288x3072x192) ----
  gemm_bt<<<dim3(48,192),256,0,stream>>>(h1, tw2, h2, 12288, 3072, 192);
  stats_kernel<<<2048,256,0,stream>>>(h2, statsRaw+128, 2359296L, 128);
  finalize_stats<<<1,16,0,stream>>>(statsRaw+128, statsFin+128, 1.f/2359296.f);

  // ---- attention + final mix ----
  attention_kernel<<<1,128,0,stream>>>(c, wqp, bqp, keys, att);
  final_mix<<<6144,256,0,stream>>>(h2, xr, tg2w, tg2b, statsFin+128, att, (float*)d_out);
}

// Round 3
// 1887.077 us; speedup vs baseline: 1.6400x; 1.6400x over previous
//
#include <hip/hip_runtime.h>
#include <hip/hip_bf16.h>

typedef unsigned short u16;
typedef unsigned int u32;

#define Tn 128
#define Fn 512
#define HWc (Tn*Fn)     // 65536 elems per channel (conv tensors)
#define EPS 1e-5f

using bf16x8 = __attribute__((ext_vector_type(8))) short;
using f32x4  = __attribute__((ext_vector_type(4))) float;

__device__ __forceinline__ float b2f(u16 x){ return __uint_as_float(((u32)x)<<16); }
__device__ __forceinline__ u16 f2b(float f){
  __hip_bfloat16 h = __float2bfloat16(f);
  return *reinterpret_cast<u16*>(&h);
}

// ---------------- zero stats ----------------
__global__ void zero_stats(float* raw){
  int i = threadIdx.x;
  if (i < 160) raw[i] = 0.f;   // 5 stages * 32 floats (sum[16], sumsq[16])
}

// ---------------- fp32 -> bf16 weight conversion ----------------
__global__ __launch_bounds__(256) void cvt_f2b(const float* __restrict__ src, u16* __restrict__ dst){
  int i = (blockIdx.x*256 + threadIdx.x)*4;
  float4 v = *(const float4*)(src + i);
  ushort4 o;
  o.x=f2b(v.x); o.y=f2b(v.y); o.z=f2b(v.z); o.w=f2b(v.w);
  *(ushort4*)(dst + i) = o;
}

// ---------------- convert+copy x (fp32) into B72 channels 48..72 (bf16) ----------------
__global__ __launch_bounds__(256) void copy_x(const float* __restrict__ x, u16* __restrict__ b72){
  int idx = blockIdx.x*256 + threadIdx.x;       // 786432 threads, 8 elems each
  long e = (long)idx*8;
  int ch = (int)(e / HWc);                      // 0..95 = b*24+c
  long r = e - (long)ch*HWc;
  int b = ch/24, c = ch%24;
  float4 v0 = *(const float4*)(x + e);
  float4 v1 = *(const float4*)(x + e + 4);
  union { int4 v; u16 u[8]; } ov;
  ov.u[0]=f2b(v0.x); ov.u[1]=f2b(v0.y); ov.u[2]=f2b(v0.z); ov.u[3]=f2b(v0.w);
  ov.u[4]=f2b(v1.x); ov.u[5]=f2b(v1.y); ov.u[6]=f2b(v1.z); ov.u[7]=f2b(v1.w);
  *(int4*)(b72 + ((long)(b*72 + 48 + c))*HWc + r) = ov.v;
}

// ---------------- direct 3x3 conv v2: one (b,o) per block, fused GN stats ----------------
template<int CIN>
__global__ __launch_bounds__(256)
void conv3x3_v2(const u16* __restrict__ in, int in_coff,
                const float* __restrict__ wt, const float* __restrict__ bias,
                u16* __restrict__ out, float* __restrict__ raw){
  __shared__ float sw[CIN*9];
  int bo = blockIdx.x >> 4;              // 0..95 = b*24+o
  int t0 = (blockIdx.x & 15) << 3;
  int o = bo % 24, b = bo / 24;
  for (int i = threadIdx.x; i < CIN*9; i += 256) sw[i] = wt[o*CIN*9 + i];
  __syncthreads();

  int fg = threadIdx.x & 31;             // 32 groups of 16 f
  int tt = threadIdx.x >> 5;             // 8 t rows
  int t = t0 + tt;
  int f0 = fg << 4;
  float bv = bias[o];
  float acc[16];
  #pragma unroll
  for (int j=0;j<16;j++) acc[j] = bv;

  const u16* bbase = in + ((long)(b*72 + in_coff))*HWc;
  bool okl = (f0 > 0), okr = (f0 + 16 < Fn);

  for (int i=0;i<CIN;i++){
    const u16* cbase = bbase + (long)i*HWc;
    float v[3][18];
    #pragma unroll
    for (int dt=0; dt<3; dt++){
      int rr = t + dt - 1;
      bool rok = (rr >= 0) && (rr < Tn);
      const u16* rp = cbase + (long)(rok ? rr : t)*Fn;
      if (rok){
        union {int4 q; u16 u[8];} p0, p1;
        p0.q = *(const int4*)(rp + f0);
        p1.q = *(const int4*)(rp + f0 + 8);
        v[dt][0]  = okl ? b2f(rp[f0-1])  : 0.f;
        v[dt][17] = okr ? b2f(rp[f0+16]) : 0.f;
        #pragma unroll
        for (int j=0;j<8;j++){ v[dt][1+j] = b2f(p0.u[j]); v[dt][9+j] = b2f(p1.u[j]); }
      } else {
        #pragma unroll
        for (int k=0;k<18;k++) v[dt][k] = 0.f;
      }
    }
    const float* wi = &sw[i*9];
    #pragma unroll
    for (int dt=0; dt<3; dt++){
      #pragma unroll
      for (int df=0; df<3; df++){
        float wv = wi[dt*3+df];
        #pragma unroll
        for (int j=0;j<16;j++) acc[j] += v[dt][df+j]*wv;
      }
    }
  }

  // fused GN stats (pre-activation)
  float s=0.f, ss=0.f;
  #pragma unroll
  for (int j=0;j<16;j++){ s += acc[j]; ss += acc[j]*acc[j]; }
  #pragma unroll
  for (int off=32; off>0; off>>=1){ s += __shfl_down(s,off,64); ss += __shfl_down(ss,off,64); }
  __shared__ float rs[4], rss[4];
  if ((threadIdx.x & 63)==0){ rs[threadIdx.x>>6]=s; rss[threadIdx.x>>6]=ss; }
  __syncthreads();
  if (threadIdx.x==0){
    int g = b*4 + o/6;
    atomicAdd(&raw[g],    rs[0]+rs[1]+rs[2]+rs[3]);
    atomicAdd(&raw[16+g], rss[0]+rss[1]+rss[2]+rss[3]);
  }

  union {int4 q; u16 u[8];} o0, o1;
  #pragma unroll
  for (int j=0;j<8;j++){ o0.u[j]=f2b(acc[j]); o1.u[j]=f2b(acc[8+j]); }
  long ob = ((long)bo*Tn + t)*Fn + f0;
  *(int4*)(out + ob)     = o0.q;
  *(int4*)(out + ob + 8) = o1.q;
}

__global__ void finalize_stats(const float* __restrict__ raw, float* __restrict__ fin, float invN){
  int g = threadIdx.x;
  if (g < 16){
    float m = raw[g]*invN;
    float v = raw[16+g]*invN - m*m;
    fin[g] = m;
    fin[16+g] = rsqrtf(v + EPS);
  }
}

// ---------------- normalize + relu (bf16 src/dst, fp32 params, layout remap) ----------------
__global__ __launch_bounds__(256)
void norm_relu(const u16* __restrict__ src, u16* __restrict__ dst,
               const float* __restrict__ gw, const float* __restrict__ gb,
               const float* __restrict__ fin, long hw, int dstC, int dcoff){
  long idx = ((long)blockIdx.x*256 + threadIdx.x)*8;
  int ch = (int)(idx / hw);            // 0..95 = b*24+c
  long r = idx - (long)ch*hw;
  int b = ch/24, c = ch%24;
  int g = b*4 + c/6;
  float m = fin[g], is = fin[16+g];
  float sc = is * gw[c];
  float off = gb[c] - m*sc;
  union { int4 v; u16 u[8]; } pk;
  pk.v = *(const int4*)(src + idx);
  union { int4 v; u16 u[8]; } ov;
  #pragma unroll
  for (int j=0;j<8;j++){
    float f = b2f(pk.u[j])*sc + off;
    ov.u[j] = f2b(f > 0.f ? f : 0.f);
  }
  *(int4*)(dst + ((long)(b*dstC + dcoff + c))*hw + r) = ov.v;
}

// ---------------- bf16 MFMA GEMM: C[M,N] = A[M,K] * Bt[N,K]^T, fused GN stats ----------------
__global__ __launch_bounds__(256)
void gemm_mfma(const u16* __restrict__ A, const u16* __restrict__ Bt, u16* __restrict__ C,
               int M, int N, int K, float* __restrict__ raw){
  int tid = threadIdx.x;
  int wave = tid >> 6, l = tid & 63;
  int r = l & 15, quad = l >> 4;
  int wm = wave >> 1, wn = wave & 1;
  long m0 = (long)blockIdx.y*64 + wm*32;
  long n0 = (long)blockIdx.x*64 + wn*32;
  f32x4 acc[2][2] = {};
  int nk = K >> 5;
  const u16* Abase = A  + m0*K + quad*8;
  const u16* Bbase = Bt + n0*K + quad*8;
  for (int ks=0; ks<nk; ks++){
    int k0 = ks*32;
    bf16x8 a0 = *(const bf16x8*)(Abase + (long)r*K + k0);
    bf16x8 a1 = *(const bf16x8*)(Abase + (long)(16+r)*K + k0);
    bf16x8 b0 = *(const bf16x8*)(Bbase + (long)r*K + k0);
    bf16x8 b1 = *(const bf16x8*)(Bbase + (long)(16+r)*K + k0);
    acc[0][0] = __builtin_amdgcn_mfma_f32_16x16x32_bf16(a0,b0,acc[0][0],0,0,0);
    acc[0][1] = __builtin_amdgcn_mfma_f32_16x16x32_bf16(a0,b1,acc[0][1],0,0,0);
    acc[1][0] = __builtin_amdgcn_mfma_f32_16x16x32_bf16(a1,b0,acc[1][0],0,0,0);
    acc[1][1] = __builtin_amdgcn_mfma_f32_16x16x32_bf16(a1,b1,acc[1][1],0,0,0);
  }
  float s=0.f, ss=0.f;
  #pragma unroll
  for (int ms=0;ms<2;ms++){
    #pragma unroll
    for (int ns=0;ns<2;ns++){
      #pragma unroll
      for (int j=0;j<4;j++){
        float v = acc[ms][ns][j];
        s += v; ss += v*v;
        C[(m0 + ms*16 + quad*4 + j)*N + n0 + ns*16 + r] = f2b(v);
      }
    }
  }
  // fused GN stats: all rows of this block lie in one (b,c) plane (64 | m0, bc = m0>>7)
  #pragma unroll
  for (int off=32; off>0; off>>=1){ s += __shfl_down(s,off,64); ss += __shfl_down(ss,off,64); }
  __shared__ float rs[4], rss[4];
  if ((tid & 63)==0){ rs[tid>>6]=s; rss[tid>>6]=ss; }
  __syncthreads();
  if (tid==0){
    int bc = (int)((blockIdx.y*64) >> 7);
    int g = (bc/24)*4 + (bc%24)/6;
    atomicAdd(&raw[g],    rs[0]+rs[1]+rs[2]+rs[3]);
    atomicAdd(&raw[16+g], rss[0]+rss[1]+rss[2]+rss[3]);
  }
}

// ---------------- attention: att[4][6] (all fp32 inputs) ----------------
__global__ void attention_kernel(const float* __restrict__ c, const float* __restrict__ wq,
                                 const float* __restrict__ bq, const float* __restrict__ keys,
                                 float* __restrict__ att){
  __shared__ float q[4][32];
  __shared__ float s[4][6];
  int t = threadIdx.x;
  if (t < 128){
    int b = t >> 5, k = t & 31;
    float a = bq[k];
    for (int j=0;j<32;j++) a += c[b*32+j] * wq[k*32+j];
    q[b][k] = a;
  }
  __syncthreads();
  if (t < 24){
    int b = t/6, n = t%6;
    float a = 0.f;
    for (int k=0;k<32;k++) a += q[b][k]*keys[k*6+n];
    s[b][n] = a * 0.17677669529663689f;   // 1/sqrt(32)
  }
  __syncthreads();
  if (t < 4){
    float mx = -1e30f;
    for (int n=0;n<6;n++) mx = fmaxf(mx, s[t][n]);
    float e[6], sm=0.f;
    for (int n=0;n<6;n++){ e[n]=expf(s[t][n]-mx); sm+=e[n]; }
    for (int n=0;n<6;n++) att[t*6+n] = e[n]/sm;
  }
}

// ---------------- final: out(fp32) = x_ + sum_n relu(gn2(h2))[...,n]*att[b,n] ----------------
__global__ __launch_bounds__(256)
void final_mix(const u16* __restrict__ h2, const u16* __restrict__ xr,
               const float* __restrict__ gw, const float* __restrict__ gb,
               const float* __restrict__ fin, const float* __restrict__ att,
               float* __restrict__ out){
  int gid = blockIdx.x*256 + threadIdx.x;   // 1,572,864 total (4 f per thread)
  int fq = gid & 127;
  int t  = (gid >> 7) & 127;
  int bc = gid >> 14;          // 0..95
  int c  = bc % 24, b = bc / 24;
  int g  = b*4 + c/6;
  float m = fin[g], is = fin[16+g];
  float sc = is * gw[c];
  float off = gb[c] - m*sc;
  float a[6];
  #pragma unroll
  for (int n=0;n<6;n++) a[n] = att[b*6+n];

  long hbase = (((long)bc*Tn + t))*3072 + (long)fq*24;
  union { int4 v[3]; u16 u[24]; } hv;
  const int4* hp = (const int4*)(h2 + hbase);
  hv.v[0]=hp[0]; hv.v[1]=hp[1]; hv.v[2]=hp[2];

  long xbase = (((long)bc*Tn + t))*Fn + (long)fq*4;
  union { unsigned long long q; u16 u[4]; } xv;
  xv.q = *(const unsigned long long*)(xr + xbase);

  float4 ov;
  float* op = &ov.x;
  #pragma unroll
  for (int j=0;j<4;j++){
    float accv = b2f(xv.u[j]);
    #pragma unroll
    for (int n=0;n<6;n++){
      float hvf = b2f(hv.u[j*6+n])*sc + off;
      hvf = hvf > 0.f ? hvf : 0.f;
      accv += hvf * a[n];
    }
    op[j] = accv;
  }
  *(float4*)(out + xbase) = ov;
}

extern "C" void kernel_launch(void* const* d_in, const int* in_sizes, int n_in,
                              void* d_out, int out_size, void* d_ws, size_t ws_size,
                              hipStream_t stream){
  const float* x   = (const float*)d_in[0];
  const float* c   = (const float*)d_in[1];
  const float* cw0 = (const float*)d_in[2];  const float* cb0 = (const float*)d_in[3];
  const float* gw0 = (const float*)d_in[4];  const float* gb0 = (const float*)d_in[5];
  const float* cw1 = (const float*)d_in[6];  const float* cb1 = (const float*)d_in[7];
  const float* gw1 = (const float*)d_in[8];  const float* gb1 = (const float*)d_in[9];
  const float* cw2 = (const float*)d_in[10]; const float* cb2 = (const float*)d_in[11];
  const float* gw2 = (const float*)d_in[12]; const float* gb2 = (const float*)d_in[13];
  const float* tw1 = (const float*)d_in[14]; const float* tg1w= (const float*)d_in[15]; const float* tg1b=(const float*)d_in[16];
  const float* tw2 = (const float*)d_in[17]; const float* tg2w= (const float*)d_in[18]; const float* tg2b=(const float*)d_in[19];
  const float* wqp = (const float*)d_in[20]; const float* bqp = (const float*)d_in[21]; const float* keys=(const float*)d_in[22];

  char* ws = (char*)d_ws;
  u16* xr = (u16*)(ws + 0);                        // 12,582,912 B  [12288,512] bf16
  u16* h1 = (u16*)(ws + 12582912);                 //  4,718,592 B  [12288,192] bf16
  float* statsRaw = (float*)(ws + 17301504);       // 160 floats
  float* statsFin = (float*)(ws + 17302528);
  float* att      = (float*)(ws + 17303552);
  u16* tw1b = (u16*)(ws + 17304576);               // 196,608 B  [192,512] bf16
  u16* tw2b = (u16*)(ws + 17501184);               // 1,179,648 B [3072,192] bf16
  char* A3 = ws + 18680832;
  u16* b72 = (u16*)A3;                             // 37,748,736 B  [4,72,128,512] bf16
  u16* Y   = (u16*)(A3 + 37748736);                // 12,582,912 B  conv scratch
  u16* h2  = (u16*)A3;                             // 75,497,472 B  [12288,3072] bf16 (reuses conv region)

  zero_stats<<<1,256,0,stream>>>(statsRaw);
  cvt_f2b<<<96,256,0,stream>>>(tw1, tw1b);         // 98304 = 96*1024
  cvt_f2b<<<576,256,0,stream>>>(tw2, tw2b);        // 589824 = 576*1024
  copy_x<<<3072,256,0,stream>>>(x, b72);

  // ---- conv block 0 ----
  conv3x3_v2<24><<<1536,256,0,stream>>>(b72, 48, cw0, cb0, Y, statsRaw+0);
  finalize_stats<<<1,16,0,stream>>>(statsRaw+0, statsFin+0, 1.f/393216.f);
  norm_relu<<<3072,256,0,stream>>>(Y, b72, gw0, gb0, statsFin+0, (long)HWc, 72, 24);

  // ---- conv block 1 ----
  conv3x3_v2<48><<<1536,256,0,stream>>>(b72, 24, cw1, cb1, Y, statsRaw+32);
  finalize_stats<<<1,16,0,stream>>>(statsRaw+32, statsFin+32, 1.f/393216.f);
  norm_relu<<<3072,256,0,stream>>>(Y, b72, gw1, gb1, statsFin+32, (long)HWc, 72, 0);

  // ---- conv block 2 -> x_ ----
  conv3x3_v2<72><<<1536,256,0,stream>>>(b72, 0, cw2, cb2, Y, statsRaw+64);
  finalize_stats<<<1,16,0,stream>>>(statsRaw+64, statsFin+64, 1.f/393216.f);
  norm_relu<<<3072,256,0,stream>>>(Y, xr, gw2, gb2, statsFin+64, (long)HWc, 24, 0);

  // ---- TDF: gemm1 (12288x192x512, MFMA) + GN + relu ----
  gemm_mfma<<<dim3(3,192),256,0,stream>>>(xr, tw1b, h1, 12288, 192, 512, statsRaw+96);
  finalize_stats<<<1,16,0,stream>>>(statsRaw+96, statsFin+96, 1.f/147456.f);
  norm_relu<<<1152,256,0,stream>>>(h1, h1, tg1w, tg1b, statsFin+96, 24576L, 24, 0);

  // ---- TDF: gemm2 (12288x3072x192, MFMA) ----
  gemm_mfma<<<dim3(48,192),256,0,stream>>>(h1, tw2b, h2, 12288, 3072, 192, statsRaw+128);
  finalize_stats<<<1,16,0,stream>>>(statsRaw+128, statsFin+128, 1.f/2359296.f);

  // ---- attention + final mix ----
  attention_kernel<<<1,128,0,stream>>>(c, wqp, bqp, keys, att);
  final_mix<<<6144,256,0,stream>>>(h2, xr, tg2w, tg2b, statsFin+128, att, (float*)d_out);
}

// Round 5
// 457.887 us; speedup vs baseline: 6.7590x; 4.1213x over previous
//
#include <hip/hip_runtime.h>
#include <hip/hip_bf16.h>

typedef unsigned short u16;
typedef unsigned int u32;

#define Tn 128
#define Fn 512
#define HWc (Tn*Fn)
#define EPS 1e-5f

using bf16x8 = __attribute__((ext_vector_type(8))) short;
using f32x4  = __attribute__((ext_vector_type(4))) float;

__device__ __forceinline__ float b2f(u16 x){ return __uint_as_float(((u32)x)<<16); }
__device__ __forceinline__ u16 f2b(float f){
  __hip_bfloat16 h = __float2bfloat16(f);
  return *reinterpret_cast<u16*>(&h);
}

// ---------------- zero stats ----------------
__global__ void zero_stats2(float* a, float* b){
  int i = threadIdx.x;
  if (i < 128) a[i] = 0.f;
  else if (i < 160) b[i-128] = 0.f;
}

// ---------------- fp32 -> bf16 weight conversion (flat) ----------------
__global__ __launch_bounds__(256) void cvt_f2b(const float* __restrict__ src, u16* __restrict__ dst){
  int i = (blockIdx.x*256 + threadIdx.x)*4;
  float4 v = *(const float4*)(src + i);
  ushort4 o;
  o.x=f2b(v.x); o.y=f2b(v.y); o.z=f2b(v.z); o.w=f2b(v.w);
  *(ushort4*)(dst + i) = o;
}

// ---------------- conv weight reorg: wr[dt][32][KP], k -> (df,ch) with gaps zeroed ----------------
__global__ __launch_bounds__(256)
void prep_wr(const float* __restrict__ w, u16* __restrict__ wr,
             int CIN, int cs, int cof, int KP){
  int i = blockIdx.x*256 + threadIdx.x;
  int tot = 96*KP;                 // 3*32*KP
  if (i >= tot) return;
  int k = i % KP; int o = (i / KP) % 32; int dt = i / (32*KP);
  float v = 0.f;
  int g = cof + k, df = g/cs, ch = g - df*cs;
  if (o < 24 && df < 3 && ch >= cof && ch < cof+CIN)
    v = w[((o*CIN + (ch-cof))*3 + dt)*3 + df];
  wr[i] = f2b(v);
}

// ---------------- copy x (CHW fp32) -> b72p NHWC ch48..72 AND xc24 NHWC compact ----------------
__global__ __launch_bounds__(256)
void copy_x2(const float* __restrict__ x, u16* __restrict__ b72p, u16* __restrict__ xc24){
  __shared__ u16 sh[24][520];
  int t = blockIdx.x & 127, b = blockIdx.x >> 7;
  const float* src = x + ((long)(b*24)*128 + t)*512;
  for (int c=0; c<24; c++){
    float2 v = *(const float2*)(src + (long)c*65536 + threadIdx.x*2);
    sh[c][threadIdx.x*2]   = f2b(v.x);
    sh[c][threadIdx.x*2+1] = f2b(v.y);
  }
  __syncthreads();
  long r72 = ((long)(b*130 + t+1))*514*72;
  long r24 = ((long)(b*130 + t+1))*514*24;
  for (int i = threadIdx.x; i < 1536; i += 256){
    int f = i/3, c0 = (i%3)*8;
    union {int4 q; u16 u[8];} o;
    #pragma unroll
    for (int j=0;j<8;j++) o.u[j] = sh[c0+j][f];
    *(int4*)(b72p + r72 + (long)(f+1)*72 + 48 + c0) = o.q;
    *(int4*)(xc24 + r24 + (long)(f+1)*24 + c0) = o.q;
  }
}

// ---------------- MFMA implicit-GEMM 3x3 conv, fused GN stats ----------------
// X: NHWC padded [4][130][514][CS]; WR: [3][32][KP] bf16; Y: NHWC [4][128][512][24]
template<int KP, int CS>
__global__ __launch_bounds__(256)
void conv_mfma(const u16* __restrict__ X, int coff, const u16* __restrict__ WR,
               const float* __restrict__ bias, u16* __restrict__ Y,
               float* __restrict__ raw){
  __shared__ float ssum[4][32], ssq[4][32];
  __shared__ float g24s[24], g24q[24];
  __shared__ __align__(16) u16 Ysh[64*24];
  int bid = blockIdx.x;
  int ft = bid & 7, t = (bid >> 3) & 127, b = bid >> 10;
  int tid = threadIdx.x, wid = tid >> 6, l = tid & 63;
  int r = l & 15, q = l >> 4;
  int f0 = ft*64 + wid*16;
  f32x4 acc0 = {}, acc1 = {};
  #pragma unroll
  for (int dt=0; dt<3; dt++){
    const u16* Ab = X + ((long)((b*130 + t+dt)*514 + f0))*CS + coff + q*8 + (long)r*CS;
    const u16* Bb = WR + dt*(32*KP) + q*8 + r*KP;
    #pragma unroll
    for (int ks=0; ks<KP/32; ks++){
      bf16x8 a  = *(const bf16x8*)(Ab + ks*32);
      bf16x8 b0 = *(const bf16x8*)(Bb + ks*32);
      bf16x8 b1 = *(const bf16x8*)(Bb + 16*KP + ks*32);
      acc0 = __builtin_amdgcn_mfma_f32_16x16x32_bf16(a,b0,acc0,0,0,0);
      acc1 = __builtin_amdgcn_mfma_f32_16x16x32_bf16(a,b1,acc1,0,0,0);
    }
  }
  float bv0 = bias[r];
  float bv1 = (r < 8) ? bias[16+r] : 0.f;
  float s0=0,q0=0,s1=0,q1=0;
  #pragma unroll
  for (int j=0;j<4;j++){
    acc0[j] += bv0; acc1[j] += bv1;
    s0 += acc0[j]; q0 += acc0[j]*acc0[j];
    s1 += acc1[j]; q1 += acc1[j]*acc1[j];
  }
  #pragma unroll
  for (int off=16; off<=32; off<<=1){
    s0 += __shfl_xor(s0, off, 64); q0 += __shfl_xor(q0, off, 64);
    s1 += __shfl_xor(s1, off, 64); q1 += __shfl_xor(q1, off, 64);
  }
  if (q == 0){
    ssum[wid][r] = s0;     ssq[wid][r] = q0;
    ssum[wid][16+r] = s1;  ssq[wid][16+r] = q1;
  }
  int fr = wid*16 + q*4;
  #pragma unroll
  for (int j=0;j<4;j++){
    Ysh[(fr+j)*24 + r] = f2b(acc0[j]);
    if (r < 8) Ysh[(fr+j)*24 + 16 + r] = f2b(acc1[j]);
  }
  __syncthreads();
  if (tid < 24){
    g24s[tid] = ssum[0][tid]+ssum[1][tid]+ssum[2][tid]+ssum[3][tid];
    g24q[tid] = ssq[0][tid]+ssq[1][tid]+ssq[2][tid]+ssq[3][tid];
  }
  __syncthreads();
  if (tid < 4){
    float as=0, aq=0;
    #pragma unroll
    for (int j=0;j<6;j++){ as += g24s[tid*6+j]; aq += g24q[tid*6+j]; }
    atomicAdd(&raw[b*4+tid], as);
    atomicAdd(&raw[16+b*4+tid], aq);
  }
  long Yb = ((long)((b*128 + t)*512) + ft*64)*24;
  const int4* sp = (const int4*)Ysh;
  for (int i = tid; i < 192; i += 256)
    *(int4*)(Y + Yb + (long)i*8) = sp[i];
}

// ---------------- finalize: raw stats -> per-(b,c) scale/offset tables ----------------
__global__ void finalize_scoff(const float* __restrict__ raw, const float* __restrict__ gw,
                               const float* __restrict__ gb, float invN,
                               float* __restrict__ scA, float* __restrict__ scB){
  int i = threadIdx.x;
  if (i < 96){
    int b = i/24, c = i%24, g = b*4 + c/6;
    float m = raw[g]*invN;
    float var = raw[16+g]*invN - m*m;
    float is = rsqrtf(var + EPS);
    float sc = is*gw[c];
    scA[i] = sc;
    scB[i] = gb[c] - m*sc;
  }
}

// ---------------- normalize+relu: Y NHWC -> b72p channel slice ----------------
__global__ __launch_bounds__(256)
void norm_relu_nhwc(const u16* __restrict__ Y, u16* __restrict__ dst, int coff,
                    const float* __restrict__ scA, const float* __restrict__ scB){
  long e = ((long)blockIdx.x*256 + threadIdx.x)*8;
  int c0 = (int)(e % 24);
  long fi = e / 24;
  int f = (int)(fi & 511);
  int bt = (int)(fi >> 9); int t = bt & 127, b = bt >> 7;
  float4 sa0 = *(const float4*)(scA + b*24 + c0);
  float4 sa1 = *(const float4*)(scA + b*24 + c0 + 4);
  float4 sb0 = *(const float4*)(scB + b*24 + c0);
  float4 sb1 = *(const float4*)(scB + b*24 + c0 + 4);
  float A[8]  = {sa0.x,sa0.y,sa0.z,sa0.w,sa1.x,sa1.y,sa1.z,sa1.w};
  float Bv[8] = {sb0.x,sb0.y,sb0.z,sb0.w,sb1.x,sb1.y,sb1.z,sb1.w};
  union {int4 q; u16 u[8];} pk; pk.q = *(const int4*)(Y + e);
  union {int4 q; u16 u[8];} o;
  #pragma unroll
  for (int j=0;j<8;j++){ float v = b2f(pk.u[j])*A[j] + Bv[j]; o.u[j] = f2b(v>0.f?v:0.f); }
  *(int4*)(dst + ((long)(b*130 + t+1)*514 + (f+1))*72 + coff + c0) = o.q;
}

// ---------------- normalize+relu + NHWC->CHW transpose (conv2 output -> xr) ----------------
__global__ __launch_bounds__(256)
void norm_relu_chw(const u16* __restrict__ Y, u16* __restrict__ xr,
                   const float* __restrict__ scA, const float* __restrict__ scB){
  __shared__ u16 sh[24][520];
  __shared__ float sA[24], sB[24];
  int t = blockIdx.x & 127, b = blockIdx.x >> 7;
  if (threadIdx.x < 24){ sA[threadIdx.x] = scA[b*24+threadIdx.x]; sB[threadIdx.x] = scB[b*24+threadIdx.x]; }
  __syncthreads();
  const u16* src = Y + ((long)(b*128+t))*12288;
  for (int i = threadIdx.x; i < 1536; i += 256){
    int e = i*8; int c0 = e % 24; int f = e / 24;
    union {int4 q; u16 u[8];} pk; pk.q = *(const int4*)(src + e);
    #pragma unroll
    for (int j=0;j<8;j++){
      float v = b2f(pk.u[j])*sA[c0+j] + sB[c0+j];
      sh[c0+j][f] = f2b(v>0.f?v:0.f);
    }
  }
  __syncthreads();
  for (int i = threadIdx.x; i < 1536; i += 256){
    int c = i >> 6, fq = (i & 63)*8;
    union {int4 q; u16 u[8];} o;
    #pragma unroll
    for (int j=0;j<8;j++) o.u[j] = sh[c][fq+j];
    *(int4*)(xr + ((long)((b*24+c)*128 + t))*512 + fq) = o.q;
  }
}

// ---------------- elementwise normalize+relu on CHW rows (h1, rowlen 192) ----------------
__global__ __launch_bounds__(256)
void norm_chw(u16* __restrict__ h, const float* __restrict__ scA, const float* __restrict__ scB){
  long e = ((long)blockIdx.x*256 + threadIdx.x)*8;
  long row = e / 192;
  int c = (int)((row >> 7) % 24);
  int b = (int)(row / 3072);
  float sc = scA[b*24+c], off = scB[b*24+c];
  union {int4 q; u16 u[8];} pk; pk.q = *(const int4*)(h + e);
  #pragma unroll
  for (int j=0;j<8;j++){ float v = b2f(pk.u[j])*sc + off; pk.u[j] = f2b(v>0.f?v:0.f); }
  *(int4*)(h + e) = pk.q;
}

// ---------------- bf16 MFMA GEMM: C[M,N] = A[M,K] * Bt[N,K]^T, fused GN stats ----------------
__global__ __launch_bounds__(256)
void gemm_mfma(const u16* __restrict__ A, const u16* __restrict__ Bt, u16* __restrict__ C,
               int M, int N, int K, float* __restrict__ raw){
  int tid = threadIdx.x;
  int wave = tid >> 6, l = tid & 63;
  int r = l & 15, quad = l >> 4;
  int wm = wave >> 1, wn = wave & 1;
  long m0 = (long)blockIdx.y*64 + wm*32;
  long n0 = (long)blockIdx.x*64 + wn*32;
  f32x4 acc[2][2] = {};
  int nk = K >> 5;
  const u16* Abase = A  + m0*K + quad*8;
  const u16* Bbase = Bt + n0*K + quad*8;
  for (int ks=0; ks<nk; ks++){
    int k0 = ks*32;
    bf16x8 a0 = *(const bf16x8*)(Abase + (long)r*K + k0);
    bf16x8 a1 = *(const bf16x8*)(Abase + (long)(16+r)*K + k0);
    bf16x8 b0 = *(const bf16x8*)(Bbase + (long)r*K + k0);
    bf16x8 b1 = *(const bf16x8*)(Bbase + (long)(16+r)*K + k0);
    acc[0][0] = __builtin_amdgcn_mfma_f32_16x16x32_bf16(a0,b0,acc[0][0],0,0,0);
    acc[0][1] = __builtin_amdgcn_mfma_f32_16x16x32_bf16(a0,b1,acc[0][1],0,0,0);
    acc[1][0] = __builtin_amdgcn_mfma_f32_16x16x32_bf16(a1,b0,acc[1][0],0,0,0);
    acc[1][1] = __builtin_amdgcn_mfma_f32_16x16x32_bf16(a1,b1,acc[1][1],0,0,0);
  }
  float s=0.f, ss=0.f;
  #pragma unroll
  for (int ms=0;ms<2;ms++){
    #pragma unroll
    for (int ns=0;ns<2;ns++){
      #pragma unroll
      for (int j=0;j<4;j++){
        float v = acc[ms][ns][j];
        s += v; ss += v*v;
        C[(m0 + ms*16 + quad*4 + j)*N + n0 + ns*16 + r] = f2b(v);
      }
    }
  }
  #pragma unroll
  for (int off=32; off>0; off>>=1){ s += __shfl_down(s,off,64); ss += __shfl_down(ss,off,64); }
  __shared__ float rs[4], rss[4];
  if ((tid & 63)==0){ rs[tid>>6]=s; rss[tid>>6]=ss; }
  __syncthreads();
  if (tid==0){
    int bc = (int)((blockIdx.y*64) >> 7);
    int g = (bc/24)*4 + (bc%24)/6;
    atomicAdd(&raw[g],    rs[0]+rs[1]+rs[2]+rs[3]);
    atomicAdd(&raw[16+g], rss[0]+rss[1]+rss[2]+rss[3]);
  }
}

// ---------------- attention: att[4][6] (fp32) ----------------
__global__ void attention_kernel(const float* __restrict__ c, const float* __restrict__ wq,
                                 const float* __restrict__ bq, const float* __restrict__ keys,
                                 float* __restrict__ att){
  __shared__ float q[4][32];
  __shared__ float s[4][6];
  int t = threadIdx.x;
  if (t < 128){
    int b = t >> 5, k = t & 31;
    float a = bq[k];
    for (int j=0;j<32;j++) a += c[b*32+j] * wq[k*32+j];
    q[b][k] = a;
  }
  __syncthreads();
  if (t < 24){
    int b = t/6, n = t%6;
    float a = 0.f;
    for (int k=0;k<32;k++) a += q[b][k]*keys[k*6+n];
    s[b][n] = a * 0.17677669529663689f;
  }
  __syncthreads();
  if (t < 4){
    float mx = -1e30f;
    for (int n=0;n<6;n++) mx = fmaxf(mx, s[t][n]);
    float e[6], sm=0.f;
    for (int n=0;n<6;n++){ e[n]=expf(s[t][n]-mx); sm+=e[n]; }
    for (int n=0;n<6;n++) att[t*6+n] = e[n]/sm;
  }
}

// ---------------- final: out(fp32) = x_ + sum_n relu(gn2(h2))[...,n]*att[b,n] ----------------
__global__ __launch_bounds__(256)
void final_mix(const u16* __restrict__ h2, const u16* __restrict__ xr,
               const float* __restrict__ scA, const float* __restrict__ scB,
               const float* __restrict__ att, float* __restrict__ out){
  int gid = blockIdx.x*256 + threadIdx.x;
  int fq = gid & 127;
  int t  = (gid >> 7) & 127;
  int bc = gid >> 14;
  int c  = bc % 24, b = bc / 24;
  float sc = scA[b*24+c];
  float off = scB[b*24+c];
  float a[6];
  #pragma unroll
  for (int n=0;n<6;n++) a[n] = att[b*6+n];

  long hbase = (((long)bc*Tn + t))*3072 + (long)fq*24;
  union { int4 v[3]; u16 u[24]; } hv;
  const int4* hp = (const int4*)(h2 + hbase);
  hv.v[0]=hp[0]; hv.v[1]=hp[1]; hv.v[2]=hp[2];

  long xbase = (((long)bc*Tn + t))*Fn + (long)fq*4;
  union { unsigned long long q; u16 u[4]; } xv;
  xv.q = *(const unsigned long long*)(xr + xbase);

  float4 ov;
  float* op = &ov.x;
  #pragma unroll
  for (int j=0;j<4;j++){
    float accv = b2f(xv.u[j]);
    #pragma unroll
    for (int n=0;n<6;n++){
      float hvf = b2f(hv.u[j*6+n])*sc + off;
      hvf = hvf > 0.f ? hvf : 0.f;
      accv += hvf * a[n];
    }
    op[j] = accv;
  }
  *(float4*)(out + xbase) = ov;
}

extern "C" void kernel_launch(void* const* d_in, const int* in_sizes, int n_in,
                              void* d_out, int out_size, void* d_ws, size_t ws_size,
                              hipStream_t stream){
  const float* x   = (const float*)d_in[0];
  const float* c   = (const float*)d_in[1];
  const float* cw0 = (const float*)d_in[2];  const float* cb0 = (const float*)d_in[3];
  const float* gw0 = (const float*)d_in[4];  const float* gb0 = (const float*)d_in[5];
  const float* cw1 = (const float*)d_in[6];  const float* cb1 = (const float*)d_in[7];
  const float* gw1 = (const float*)d_in[8];  const float* gb1 = (const float*)d_in[9];
  const float* cw2 = (const float*)d_in[10]; const float* cb2 = (const float*)d_in[11];
  const float* gw2 = (const float*)d_in[12]; const float* gb2 = (const float*)d_in[13];
  const float* tw1 = (const float*)d_in[14]; const float* tg1w= (const float*)d_in[15]; const float* tg1b=(const float*)d_in[16];
  const float* tw2 = (const float*)d_in[17]; const float* tg2w= (const float*)d_in[18]; const float* tg2b=(const float*)d_in[19];
  const float* wqp = (const float*)d_in[20]; const float* bqp = (const float*)d_in[21]; const float* keys=(const float*)d_in[22];

  char* ws = (char*)d_ws;
  // ---- fixed front matter (outside h2 span) ----
  u16*   xr     = (u16*)(ws + 0);               // 12,582,912 B  [12288,512] bf16 CHW
  u16*   h1     = (u16*)(ws + 12582912);        //  4,718,592 B  [12288,192]
  u16*   tw1b   = (u16*)(ws + 17301504);        //    196,608 B
  u16*   tw2b   = (u16*)(ws + 17498112);        //  1,179,648 B
  float* stats5 = (float*)(ws + 18677760);      //        128 B
  float* scoff5 = (float*)(ws + 18677888);      //        768 B  [96 scA][96 scB]
  float* att    = (float*)(ws + 18678656);      //        128 B
  // ---- h2 span (reused during conv phase) ----
  u16*   h2     = (u16*)(ws + 18680832);        // 75,497,472 B  [12288,3072]
  u16*   Y      = (u16*)(ws + 18680832);        // 12,582,912 B  NHWC conv out [4,128,512,24] (6,291,456 elems)
  u16*   b72p   = (u16*)(ws + 31263744);        // 38,488,320 B  NHWC padded [4,130,514,72]
  u16*   xc24   = (u16*)(ws + 69752064);        // 12,829,440 B (+256 slack) NHWC padded [4,130,514,24]
  float* stats14= (float*)(ws + 82581760);      //        512 B  4 stages x 32
  float* scoff14= (float*)(ws + 82582272);      //      3,072 B  4 stages x 192
  u16*   wr0    = (u16*)(ws + 82585344);        //     18,432 B  [3][32][96]
  u16*   wr1    = (u16*)(ws + 82603776);        //     36,864 B  [3][32][192]
  u16*   wr2    = (u16*)(ws + 82640640);        //     43,008 B  [3][32][224]
  // total footprint: max(82,683,648, 94,178,304) = 94,178,304 (== round-2 proven size)

  // zero padded activation buffers (borders must be 0; also over-read slack)
  hipMemsetAsync(b72p, 0, 38488320, stream);
  hipMemsetAsync(xc24, 0, 12829440 + 256, stream);
  zero_stats2<<<1,256,0,stream>>>(stats14, stats5);

  // weight preps
  prep_wr<<<36,256,0,stream>>>(cw0, wr0, 24, 24, 0, 96);
  prep_wr<<<72,256,0,stream>>>(cw1, wr1, 48, 72, 24, 192);
  prep_wr<<<84,256,0,stream>>>(cw2, wr2, 72, 72, 0, 224);
  cvt_f2b<<<96,256,0,stream>>>(tw1, tw1b);
  cvt_f2b<<<576,256,0,stream>>>(tw2, tw2b);
  copy_x2<<<512,256,0,stream>>>(x, b72p, xc24);
  attention_kernel<<<1,128,0,stream>>>(c, wqp, bqp, keys, att);

  // ---- conv block 0 (reads compact xc24) ----
  conv_mfma<96,24><<<4096,256,0,stream>>>(xc24, 0, wr0, cb0, Y, stats14+0);
  finalize_scoff<<<1,96,0,stream>>>(stats14+0, gw0, gb0, 1.f/393216.f, scoff14+0, scoff14+96);
  norm_relu_nhwc<<<3072,256,0,stream>>>(Y, b72p, 24, scoff14+0, scoff14+96);

  // ---- conv block 1 (reads b72p ch 24..72) ----
  conv_mfma<192,72><<<4096,256,0,stream>>>(b72p, 24, wr1, cb1, Y, stats14+32);
  finalize_scoff<<<1,96,0,stream>>>(stats14+32, gw1, gb1, 1.f/393216.f, scoff14+192, scoff14+288);
  norm_relu_nhwc<<<3072,256,0,stream>>>(Y, b72p, 0, scoff14+192, scoff14+288);

  // ---- conv block 2 (reads b72p ch 0..72) -> xr (CHW) ----
  conv_mfma<224,72><<<4096,256,0,stream>>>(b72p, 0, wr2, cb2, Y, stats14+64);
  finalize_scoff<<<1,96,0,stream>>>(stats14+64, gw2, gb2, 1.f/393216.f, scoff14+384, scoff14+480);
  norm_relu_chw<<<512,256,0,stream>>>(Y, xr, scoff14+384, scoff14+480);

  // ---- TDF: gemm1 + GN + relu ----
  gemm_mfma<<<dim3(3,192),256,0,stream>>>(xr, tw1b, h1, 12288, 192, 512, stats14+96);
  finalize_scoff<<<1,96,0,stream>>>(stats14+96, tg1w, tg1b, 1.f/147456.f, scoff14+576, scoff14+672);
  norm_chw<<<1152,256,0,stream>>>(h1, scoff14+576, scoff14+672);

  // ---- TDF: gemm2 ----
  gemm_mfma<<<dim3(48,192),256,0,stream>>>(h1, tw2b, h2, 12288, 3072, 192, stats5);
  finalize_scoff<<<1,96,0,stream>>>(stats5, tg2w, tg2b, 1.f/2359296.f, scoff5, scoff5+96);

  // ---- final mix ----
  final_mix<<<6144,256,0,stream>>>(h2, xr, scoff5, scoff5+96, att, (float*)d_out);
}

// Round 6
// 285.289 us; speedup vs baseline: 10.8481x; 1.6050x over previous
//
#include <hip/hip_runtime.h>
#include <hip/hip_bf16.h>

typedef unsigned short u16;
typedef unsigned int u32;

#define Tn 128
#define Fn 512
#define HWc (Tn*Fn)
#define EPS 1e-5f

using bf16x8 = __attribute__((ext_vector_type(8))) short;
using f32x4  = __attribute__((ext_vector_type(4))) float;

__device__ __forceinline__ float b2f(u16 x){ return __uint_as_float(((u32)x)<<16); }
__device__ __forceinline__ u16 f2b(float f){
  __hip_bfloat16 h = __float2bfloat16(f);
  return *reinterpret_cast<u16*>(&h);
}

// async global->LDS, 16B per lane (wave-uniform LDS base + lane*16 ordering)
__device__ __forceinline__ void gload16(const u16* g, u16* l){
  __builtin_amdgcn_global_load_lds((const __attribute__((address_space(1))) void*)g,
                                   (__attribute__((address_space(3))) void*)l, 16, 0, 0);
}

// ---------------- zero stats ----------------
__global__ void zero_stats2(float* a, float* b){
  int i = threadIdx.x;
  if (i < 128) a[i] = 0.f;
  else if (i < 160) b[i-128] = 0.f;
}

// ---------------- fp32 -> bf16 weight conversion (flat) ----------------
__global__ __launch_bounds__(256) void cvt_f2b(const float* __restrict__ src, u16* __restrict__ dst){
  int i = (blockIdx.x*256 + threadIdx.x)*4;
  float4 v = *(const float4*)(src + i);
  ushort4 o;
  o.x=f2b(v.x); o.y=f2b(v.y); o.z=f2b(v.z); o.w=f2b(v.w);
  *(ushort4*)(dst + i) = o;
}

// ---------------- conv weight reorg: wr[dt][32][KP], k -> (df,ch) with gaps zeroed ----------------
__global__ __launch_bounds__(256)
void prep_wr(const float* __restrict__ w, u16* __restrict__ wr,
             int CIN, int cs, int cof, int KP){
  int i = blockIdx.x*256 + threadIdx.x;
  int tot = 96*KP;                 // 3*32*KP
  if (i >= tot) return;
  int k = i % KP; int o = (i / KP) % 32; int dt = i / (32*KP);
  float v = 0.f;
  int g = cof + k, df = g/cs, ch = g - df*cs;
  if (o < 24 && df < 3 && ch >= cof && ch < cof+CIN)
    v = w[((o*CIN + (ch-cof))*3 + dt)*3 + df];
  wr[i] = f2b(v);
}

// ---------------- copy x (CHW fp32) -> b72p NHWC ch48..72 AND xc24 NHWC compact ----------------
__global__ __launch_bounds__(256)
void copy_x2(const float* __restrict__ x, u16* __restrict__ b72p, u16* __restrict__ xc24){
  __shared__ u16 sh[24][520];
  int t = blockIdx.x & 127, b = blockIdx.x >> 7;
  const float* src = x + ((long)(b*24)*128 + t)*512;
  for (int c=0; c<24; c++){
    float2 v = *(const float2*)(src + (long)c*65536 + threadIdx.x*2);
    sh[c][threadIdx.x*2]   = f2b(v.x);
    sh[c][threadIdx.x*2+1] = f2b(v.y);
  }
  __syncthreads();
  long r72 = ((long)(b*130 + t+1))*514*72;
  long r24 = ((long)(b*130 + t+1))*514*24;
  for (int i = threadIdx.x; i < 1536; i += 256){
    int f = i/3, c0 = (i%3)*8;
    union {int4 q; u16 u[8];} o;
    #pragma unroll
    for (int j=0;j<8;j++) o.u[j] = sh[c0+j][f];
    *(int4*)(b72p + r72 + (long)(f+1)*72 + 48 + c0) = o.q;
    *(int4*)(xc24 + r24 + (long)(f+1)*24 + c0) = o.q;
  }
}

// ---------------- MFMA implicit-GEMM 3x3 conv v3 ----------------
// weights staged in LDS; each block: 128 f x 24 ch for one (b,t); 4 waves x (32f x 32ch)
// X: NHWC padded [4][130][514][CS]; WR: [3][32][KP] bf16; Y: NHWC [4][128][512][24]
template<int KP, int CS>
__global__ __launch_bounds__(256)
void conv_mfma(const u16* __restrict__ X, int coff, const u16* __restrict__ WR,
               const float* __restrict__ bias, u16* __restrict__ Y,
               float* __restrict__ raw){
  __shared__ u16 WS[3*32*KP];
  __shared__ float ssum[4][32], ssq[4][32];
  __shared__ float g24s[24], g24q[24];
  __shared__ __align__(16) u16 Ysh[128*24];
  int bid = blockIdx.x;
  int ft = bid & 3, t = (bid >> 2) & 127, b = bid >> 9;
  int tid = threadIdx.x, wid = tid >> 6, l = tid & 63;
  int r = l & 15, q = l >> 4;
  int f0w = ft*128 + wid*32;

  for (int i = tid*8; i < 3*32*KP; i += 2048)
    *(int4*)(WS + i) = *(const int4*)(WR + i);
  __syncthreads();

  f32x4 acc[2][2] = {};
  #pragma unroll
  for (int dt=0; dt<3; dt++){
    const u16* Ab = X + ((long)((b*130 + t+dt)*514 + f0w + r))*CS + coff + q*8;
    const u16* Bb = WS + dt*(32*KP) + r*KP + q*8;
    #pragma unroll
    for (int ks=0; ks<KP/32; ks++){
      bf16x8 a0 = *(const bf16x8*)(Ab + ks*32);
      bf16x8 a1 = *(const bf16x8*)(Ab + (long)16*CS + ks*32);
      bf16x8 b0 = *(const bf16x8*)(Bb + ks*32);
      bf16x8 b1 = *(const bf16x8*)(Bb + 16*KP + ks*32);
      acc[0][0] = __builtin_amdgcn_mfma_f32_16x16x32_bf16(a0,b0,acc[0][0],0,0,0);
      acc[0][1] = __builtin_amdgcn_mfma_f32_16x16x32_bf16(a0,b1,acc[0][1],0,0,0);
      acc[1][0] = __builtin_amdgcn_mfma_f32_16x16x32_bf16(a1,b0,acc[1][0],0,0,0);
      acc[1][1] = __builtin_amdgcn_mfma_f32_16x16x32_bf16(a1,b1,acc[1][1],0,0,0);
    }
  }
  float bv0 = bias[r];
  float bv1 = (r < 8) ? bias[16+r] : 0.f;
  float s0=0,q0=0,s1=0,q1=0;
  #pragma unroll
  for (int m=0;m<2;m++){
    #pragma unroll
    for (int j=0;j<4;j++){
      acc[m][0][j] += bv0; acc[m][1][j] += bv1;
      s0 += acc[m][0][j]; q0 += acc[m][0][j]*acc[m][0][j];
      s1 += acc[m][1][j]; q1 += acc[m][1][j]*acc[m][1][j];
    }
  }
  #pragma unroll
  for (int off=16; off<=32; off<<=1){
    s0 += __shfl_xor(s0, off, 64); q0 += __shfl_xor(q0, off, 64);
    s1 += __shfl_xor(s1, off, 64); q1 += __shfl_xor(q1, off, 64);
  }
  if (q == 0){
    ssum[wid][r] = s0;     ssq[wid][r] = q0;
    ssum[wid][16+r] = s1;  ssq[wid][16+r] = q1;
  }
  #pragma unroll
  for (int m=0;m<2;m++){
    int fr = wid*32 + m*16 + q*4;
    #pragma unroll
    for (int j=0;j<4;j++){
      Ysh[(fr+j)*24 + r] = f2b(acc[m][0][j]);
      if (r < 8) Ysh[(fr+j)*24 + 16 + r] = f2b(acc[m][1][j]);
    }
  }
  __syncthreads();
  if (tid < 24){
    g24s[tid] = ssum[0][tid]+ssum[1][tid]+ssum[2][tid]+ssum[3][tid];
    g24q[tid] = ssq[0][tid]+ssq[1][tid]+ssq[2][tid]+ssq[3][tid];
  }
  __syncthreads();
  if (tid < 4){
    float as=0, aq=0;
    #pragma unroll
    for (int j=0;j<6;j++){ as += g24s[tid*6+j]; aq += g24q[tid*6+j]; }
    atomicAdd(&raw[b*4+tid], as);
    atomicAdd(&raw[16+b*4+tid], aq);
  }
  long Yb = ((long)((b*128 + t)*512) + ft*128)*24;
  const int4* sp = (const int4*)Ysh;
  for (int i = tid; i < 384; i += 256)
    *(int4*)(Y + Yb + (long)i*8) = sp[i];
}

// ---------------- finalize: raw stats -> per-(b,c) scale/offset tables ----------------
__global__ void finalize_scoff(const float* __restrict__ raw, const float* __restrict__ gw,
                               const float* __restrict__ gb, float invN,
                               float* __restrict__ scA, float* __restrict__ scB){
  int i = threadIdx.x;
  if (i < 96){
    int b = i/24, c = i%24, g = b*4 + c/6;
    float m = raw[g]*invN;
    float var = raw[16+g]*invN - m*m;
    float is = rsqrtf(var + EPS);
    float sc = is*gw[c];
    scA[i] = sc;
    scB[i] = gb[c] - m*sc;
  }
}

// ---------------- normalize+relu: Y NHWC -> b72p channel slice ----------------
__global__ __launch_bounds__(256)
void norm_relu_nhwc(const u16* __restrict__ Y, u16* __restrict__ dst, int coff,
                    const float* __restrict__ scA, const float* __restrict__ scB){
  long e = ((long)blockIdx.x*256 + threadIdx.x)*8;
  int c0 = (int)(e % 24);
  long fi = e / 24;
  int f = (int)(fi & 511);
  int bt = (int)(fi >> 9); int t = bt & 127, b = bt >> 7;
  float4 sa0 = *(const float4*)(scA + b*24 + c0);
  float4 sa1 = *(const float4*)(scA + b*24 + c0 + 4);
  float4 sb0 = *(const float4*)(scB + b*24 + c0);
  float4 sb1 = *(const float4*)(scB + b*24 + c0 + 4);
  float A[8]  = {sa0.x,sa0.y,sa0.z,sa0.w,sa1.x,sa1.y,sa1.z,sa1.w};
  float Bv[8] = {sb0.x,sb0.y,sb0.z,sb0.w,sb1.x,sb1.y,sb1.z,sb1.w};
  union {int4 q; u16 u[8];} pk; pk.q = *(const int4*)(Y + e);
  union {int4 q; u16 u[8];} o;
  #pragma unroll
  for (int j=0;j<8;j++){ float v = b2f(pk.u[j])*A[j] + Bv[j]; o.u[j] = f2b(v>0.f?v:0.f); }
  *(int4*)(dst + ((long)(b*130 + t+1)*514 + (f+1))*72 + coff + c0) = o.q;
}

// ---------------- normalize+relu + NHWC->CHW transpose (conv2 output -> xr) ----------------
__global__ __launch_bounds__(256)
void norm_relu_chw(const u16* __restrict__ Y, u16* __restrict__ xr,
                   const float* __restrict__ scA, const float* __restrict__ scB){
  __shared__ u16 sh[24][520];
  __shared__ float sA[24], sB[24];
  int t = blockIdx.x & 127, b = blockIdx.x >> 7;
  if (threadIdx.x < 24){ sA[threadIdx.x] = scA[b*24+threadIdx.x]; sB[threadIdx.x] = scB[b*24+threadIdx.x]; }
  __syncthreads();
  const u16* src = Y + ((long)(b*128+t))*12288;
  for (int i = threadIdx.x; i < 1536; i += 256){
    int e = i*8; int c0 = e % 24; int f = e / 24;
    union {int4 q; u16 u[8];} pk; pk.q = *(const int4*)(src + e);
    #pragma unroll
    for (int j=0;j<8;j++){
      float v = b2f(pk.u[j])*sA[c0+j] + sB[c0+j];
      sh[c0+j][f] = f2b(v>0.f?v:0.f);
    }
  }
  __syncthreads();
  for (int i = threadIdx.x; i < 1536; i += 256){
    int c = i >> 6, fq = (i & 63)*8;
    union {int4 q; u16 u[8];} o;
    #pragma unroll
    for (int j=0;j<8;j++) o.u[j] = sh[c][fq+j];
    *(int4*)(xr + ((long)((b*24+c)*128 + t))*512 + fq) = o.q;
  }
}

// ---------------- elementwise normalize+relu on CHW rows (h1, rowlen 192) ----------------
__global__ __launch_bounds__(256)
void norm_chw(u16* __restrict__ h, const float* __restrict__ scA, const float* __restrict__ scB){
  long e = ((long)blockIdx.x*256 + threadIdx.x)*8;
  long row = e / 192;
  int c = (int)((row >> 7) % 24);
  int b = (int)(row / 3072);
  float sc = scA[b*24+c], off = scB[b*24+c];
  union {int4 q; u16 u[8];} pk; pk.q = *(const int4*)(h + e);
  #pragma unroll
  for (int j=0;j<8;j++){ float v = b2f(pk.u[j])*sc + off; pk.u[j] = f2b(v>0.f?v:0.f); }
  *(int4*)(h + e) = pk.q;
}

// ---------------- LDS-staged MFMA GEMM (m97 structure), fused GN stats ----------------
// C[M,N](bf16) = A[M,K](bf16) * Bt[N,K](bf16)^T. Tile 128 x (NF*32), BK=32. 4 waves 2x2.
template<int NF>
__global__ __launch_bounds__(256)
void gemm_lds(const u16* __restrict__ A, const u16* __restrict__ Bt, u16* __restrict__ C,
              int N, int K, float* __restrict__ raw){
  constexpr int BN = NF*32;
  __shared__ __align__(16) u16 As[128*32];
  __shared__ __align__(16) u16 Bs[BN*32];
  int tid = threadIdx.x, wid = tid >> 6, l = tid & 63;
  int r = l & 15, q = l >> 4;
  int wr = wid >> 1, wc = wid & 1;
  long m0 = (long)blockIdx.y*128;
  int n0 = blockIdx.x*BN;

  f32x4 acc[4][NF];
  #pragma unroll
  for (int mf=0;mf<4;mf++)
    #pragma unroll
    for (int nf=0;nf<NF;nf++) acc[mf][nf] = (f32x4){0.f,0.f,0.f,0.f};

  for (int kt=0; kt<K; kt+=32){
    #pragma unroll
    for (int j=0;j<2;j++){
      int idx = (wid*2+j)*64 + l;           // 0..511
      int row = idx>>2, ch = idx&3;
      gload16(A + (m0+row)*K + kt + ch*8, As + idx*8);
    }
    #pragma unroll
    for (int j=0;j<NF/2;j++){
      int idx = (wid*(NF/2)+j)*64 + l;      // 0..BN*4
      int row = idx>>2, ch = idx&3;
      gload16(Bt + (long)(n0+row)*K + kt + ch*8, Bs + idx*8);
    }
    __syncthreads();
    bf16x8 af[4], bf[NF];
    #pragma unroll
    for (int mf=0;mf<4;mf++) af[mf] = *(const bf16x8*)(As + (wr*64 + mf*16 + r)*32 + q*8);
    #pragma unroll
    for (int nf=0;nf<NF;nf++) bf[nf] = *(const bf16x8*)(Bs + (wc*(NF*16) + nf*16 + r)*32 + q*8);
    #pragma unroll
    for (int mf=0;mf<4;mf++)
      #pragma unroll
      for (int nf=0;nf<NF;nf++)
        acc[mf][nf] = __builtin_amdgcn_mfma_f32_16x16x32_bf16(af[mf], bf[nf], acc[mf][nf], 0,0,0);
    __syncthreads();
  }

  float s=0.f, ss=0.f;
  #pragma unroll
  for (int mf=0;mf<4;mf++){
    #pragma unroll
    for (int nf=0;nf<NF;nf++){
      #pragma unroll
      for (int j=0;j<4;j++){
        float v = acc[mf][nf][j];
        s += v; ss += v*v;
        C[(m0 + wr*64 + mf*16 + q*4 + j)*N + n0 + wc*(NF*16) + nf*16 + r] = f2b(v);
      }
    }
  }
  #pragma unroll
  for (int off=32; off>0; off>>=1){ s += __shfl_down(s,off,64); ss += __shfl_down(ss,off,64); }
  __shared__ float rs[4], rss[4];
  if (l==0){ rs[wid]=s; rss[wid]=ss; }
  __syncthreads();
  if (tid==0){
    int bc = (int)(m0 >> 7);
    int g = (bc/24)*4 + (bc%24)/6;
    atomicAdd(&raw[g],    rs[0]+rs[1]+rs[2]+rs[3]);
    atomicAdd(&raw[16+g], rss[0]+rss[1]+rss[2]+rss[3]);
  }
}

// ---------------- attention: att[4][6] (fp32) ----------------
__global__ void attention_kernel(const float* __restrict__ c, const float* __restrict__ wq,
                                 const float* __restrict__ bq, const float* __restrict__ keys,
                                 float* __restrict__ att){
  __shared__ float q[4][32];
  __shared__ float s[4][6];
  int t = threadIdx.x;
  if (t < 128){
    int b = t >> 5, k = t & 31;
    float a = bq[k];
    for (int j=0;j<32;j++) a += c[b*32+j] * wq[k*32+j];
    q[b][k] = a;
  }
  __syncthreads();
  if (t < 24){
    int b = t/6, n = t%6;
    float a = 0.f;
    for (int k=0;k<32;k++) a += q[b][k]*keys[k*6+n];
    s[b][n] = a * 0.17677669529663689f;
  }
  __syncthreads();
  if (t < 4){
    float mx = -1e30f;
    for (int n=0;n<6;n++) mx = fmaxf(mx, s[t][n]);
    float e[6], sm=0.f;
    for (int n=0;n<6;n++){ e[n]=expf(s[t][n]-mx); sm+=e[n]; }
    for (int n=0;n<6;n++) att[t*6+n] = e[n]/sm;
  }
}

// ---------------- final: out(fp32) = x_ + sum_n relu(gn2(h2))[...,n]*att[b,n] ----------------
__global__ __launch_bounds__(256)
void final_mix(const u16* __restrict__ h2, const u16* __restrict__ xr,
               const float* __restrict__ scA, const float* __restrict__ scB,
               const float* __restrict__ att, float* __restrict__ out){
  int gid = blockIdx.x*256 + threadIdx.x;
  int fq = gid & 127;
  int t  = (gid >> 7) & 127;
  int bc = gid >> 14;
  int c  = bc % 24, b = bc / 24;
  float sc = scA[b*24+c];
  float off = scB[b*24+c];
  float a[6];
  #pragma unroll
  for (int n=0;n<6;n++) a[n] = att[b*6+n];

  long hbase = (((long)bc*Tn + t))*3072 + (long)fq*24;
  union { int4 v[3]; u16 u[24]; } hv;
  const int4* hp = (const int4*)(h2 + hbase);
  hv.v[0]=hp[0]; hv.v[1]=hp[1]; hv.v[2]=hp[2];

  long xbase = (((long)bc*Tn + t))*Fn + (long)fq*4;
  union { unsigned long long q; u16 u[4]; } xv;
  xv.q = *(const unsigned long long*)(xr + xbase);

  float4 ov;
  float* op = &ov.x;
  #pragma unroll
  for (int j=0;j<4;j++){
    float accv = b2f(xv.u[j]);
    #pragma unroll
    for (int n=0;n<6;n++){
      float hvf = b2f(hv.u[j*6+n])*sc + off;
      hvf = hvf > 0.f ? hvf : 0.f;
      accv += hvf * a[n];
    }
    op[j] = accv;
  }
  *(float4*)(out + xbase) = ov;
}

extern "C" void kernel_launch(void* const* d_in, const int* in_sizes, int n_in,
                              void* d_out, int out_size, void* d_ws, size_t ws_size,
                              hipStream_t stream){
  const float* x   = (const float*)d_in[0];
  const float* c   = (const float*)d_in[1];
  const float* cw0 = (const float*)d_in[2];  const float* cb0 = (const float*)d_in[3];
  const float* gw0 = (const float*)d_in[4];  const float* gb0 = (const float*)d_in[5];
  const float* cw1 = (const float*)d_in[6];  const float* cb1 = (const float*)d_in[7];
  const float* gw1 = (const float*)d_in[8];  const float* gb1 = (const float*)d_in[9];
  const float* cw2 = (const float*)d_in[10]; const float* cb2 = (const float*)d_in[11];
  const float* gw2 = (const float*)d_in[12]; const float* gb2 = (const float*)d_in[13];
  const float* tw1 = (const float*)d_in[14]; const float* tg1w= (const float*)d_in[15]; const float* tg1b=(const float*)d_in[16];
  const float* tw2 = (const float*)d_in[17]; const float* tg2w= (const float*)d_in[18]; const float* tg2b=(const float*)d_in[19];
  const float* wqp = (const float*)d_in[20]; const float* bqp = (const float*)d_in[21]; const float* keys=(const float*)d_in[22];

  char* ws = (char*)d_ws;
  // ---- fixed front matter (outside h2 span) ----
  u16*   xr     = (u16*)(ws + 0);               // 12,582,912 B  [12288,512] bf16 CHW
  u16*   h1     = (u16*)(ws + 12582912);        //  4,718,592 B  [12288,192]
  u16*   tw1b   = (u16*)(ws + 17301504);        //    196,608 B
  u16*   tw2b   = (u16*)(ws + 17498112);        //  1,179,648 B
  float* stats5 = (float*)(ws + 18677760);      //        128 B
  float* scoff5 = (float*)(ws + 18677888);      //        768 B  [96 scA][96 scB]
  float* att    = (float*)(ws + 18678656);      //        128 B
  // ---- h2 span (reused during conv phase) ----
  u16*   h2     = (u16*)(ws + 18680832);        // 75,497,472 B  [12288,3072]
  u16*   Y      = (u16*)(ws + 18680832);        // 12,582,912 B  NHWC conv out [4,128,512,24]
  u16*   b72p   = (u16*)(ws + 31263744);        // 38,488,320 B  NHWC padded [4,130,514,72]
  u16*   xc24   = (u16*)(ws + 69752064);        // 12,829,440 B (+256 slack) NHWC padded [4,130,514,24]
  float* stats14= (float*)(ws + 82581760);      //        512 B  4 stages x 32
  float* scoff14= (float*)(ws + 82582272);      //      3,072 B  4 stages x 192
  u16*   wr0    = (u16*)(ws + 82585344);        //     18,432 B  [3][32][96]
  u16*   wr1    = (u16*)(ws + 82603776);        //     36,864 B  [3][32][192]
  u16*   wr2    = (u16*)(ws + 82640640);        //     43,008 B  [3][32][224]

  // zero padded activation buffers (borders must be 0; also over-read slack)
  hipMemsetAsync(b72p, 0, 38488320, stream);
  hipMemsetAsync(xc24, 0, 12829440 + 256, stream);
  zero_stats2<<<1,256,0,stream>>>(stats14, stats5);

  // weight preps
  prep_wr<<<36,256,0,stream>>>(cw0, wr0, 24, 24, 0, 96);
  prep_wr<<<72,256,0,stream>>>(cw1, wr1, 48, 72, 24, 192);
  prep_wr<<<84,256,0,stream>>>(cw2, wr2, 72, 72, 0, 224);
  cvt_f2b<<<96,256,0,stream>>>(tw1, tw1b);
  cvt_f2b<<<576,256,0,stream>>>(tw2, tw2b);
  copy_x2<<<512,256,0,stream>>>(x, b72p, xc24);
  attention_kernel<<<1,128,0,stream>>>(c, wqp, bqp, keys, att);

  // ---- conv block 0 (reads compact xc24) ----
  conv_mfma<96,24><<<2048,256,0,stream>>>(xc24, 0, wr0, cb0, Y, stats14+0);
  finalize_scoff<<<1,96,0,stream>>>(stats14+0, gw0, gb0, 1.f/393216.f, scoff14+0, scoff14+96);
  norm_relu_nhwc<<<3072,256,0,stream>>>(Y, b72p, 24, scoff14+0, scoff14+96);

  // ---- conv block 1 (reads b72p ch 24..72) ----
  conv_mfma<192,72><<<2048,256,0,stream>>>(b72p, 24, wr1, cb1, Y, stats14+32);
  finalize_scoff<<<1,96,0,stream>>>(stats14+32, gw1, gb1, 1.f/393216.f, scoff14+192, scoff14+288);
  norm_relu_nhwc<<<3072,256,0,stream>>>(Y, b72p, 0, scoff14+192, scoff14+288);

  // ---- conv block 2 (reads b72p ch 0..72) -> xr (CHW) ----
  conv_mfma<224,72><<<2048,256,0,stream>>>(b72p, 0, wr2, cb2, Y, stats14+64);
  finalize_scoff<<<1,96,0,stream>>>(stats14+64, gw2, gb2, 1.f/393216.f, scoff14+384, scoff14+480);
  norm_relu_chw<<<512,256,0,stream>>>(Y, xr, scoff14+384, scoff14+480);

  // ---- TDF: gemm1 (12288x192x512) + GN + relu ----
  gemm_lds<2><<<dim3(3,96),256,0,stream>>>(xr, tw1b, h1, 192, 512, stats14+96);
  finalize_scoff<<<1,96,0,stream>>>(stats14+96, tg1w, tg1b, 1.f/147456.f, scoff14+576, scoff14+672);
  norm_chw<<<1152,256,0,stream>>>(h1, scoff14+576, scoff14+672);

  // ---- TDF: gemm2 (12288x3072x192) ----
  gemm_lds<4><<<dim3(24,96),256,0,stream>>>(h1, tw2b, h2, 3072, 192, stats5);
  finalize_scoff<<<1,96,0,stream>>>(stats5, tg2w, tg2b, 1.f/2359296.f, scoff5, scoff5+96);

  // ---- final mix ----
  final_mix<<<6144,256,0,stream>>>(h2, xr, scoff5, scoff5+96, att, (float*)d_out);
}